// Round 3
// baseline (506.781 us; speedup 1.0000x reference)
//
#include <hip/hip_runtime.h>
#include <math.h>

typedef unsigned short u16;
typedef __attribute__((ext_vector_type(8))) short bf16x8;
typedef __attribute__((ext_vector_type(4))) float f32x4;

#define NN 32768      // total nodes
#define EDGES 524288  // total edges
#define NB 64         // graphs
#define NPG 512       // nodes per graph
#define KEEP 256      // kept per graph
#define D 512         // feature dim

__device__ __forceinline__ float b2f(u16 h){ return __uint_as_float(((unsigned)h)<<16); }
__device__ __forceinline__ u16 f2b(float f){
  unsigned u = __float_as_uint(f);
  unsigned r = u + 0x7FFFu + ((u>>16)&1u);   // RNE
  return (u16)(r>>16);
}

// ---------- dtype detection: are float inputs f32 (flag=1) or bf16 (flag=0)? ----------
__global__ __launch_bounds__(256) void detect_kernel(const u16* __restrict__ xb, int* __restrict__ flags){
  __shared__ int cnt;
  if (threadIdx.x==0) cnt = 0;
  __syncthreads();
  u16 v = xb[threadIdx.x];
  int e = (v>>7)&0xFF;
  if (e > 140) atomicAdd(&cnt, 1);   // raw f32 mantissa halves have random exponent fields
  __syncthreads();
  if (threadIdx.x==0){ flags[0] = (cnt > 8) ? 1 : 0; flags[1] = 1; }
}

__global__ __launch_bounds__(256) void zero3_kernel(int* __restrict__ p){
  p[blockIdx.x*256 + threadIdx.x] = 0;   // covers dego, degi, cursor (3*NN ints)
}

// ---------------- graph preprocessing ----------------

__global__ __launch_bounds__(256) void deg_kernel(const int* __restrict__ src, const int* __restrict__ dst,
                                                  int* __restrict__ dego, int* __restrict__ degi){
  int e = blockIdx.x*256 + threadIdx.x;
  if (e < EDGES){
    atomicAdd(&dego[src[e]], 1);
    atomicAdd(&degi[dst[e]], 1);
  }
}

__global__ __launch_bounds__(256) void norm_kernel(const int* __restrict__ dego, const int* __restrict__ degi,
                                                   float* __restrict__ no, float* __restrict__ ni){
  int v = blockIdx.x*256 + threadIdx.x;
  if (v < NN){
    int a = dego[v]; if (a < 1) a = 1;
    int b = degi[v]; if (b < 1) b = 1;
    no[v] = (float)(1.0/sqrt((double)a));
    ni[v] = (float)(1.0/sqrt((double)b));
  }
}

__global__ __launch_bounds__(1024) void scan_kernel(const int* __restrict__ degi, int* __restrict__ rowp){
  __shared__ int sums[1024];
  int t = threadIdx.x;
  int base = t*32;
  int loc[32];
  int s = 0;
  #pragma unroll
  for (int i=0;i<32;i++){ loc[i] = s; s += degi[base+i]; }
  sums[t] = s;
  __syncthreads();
  for (int off=1; off<1024; off<<=1){
    int v = (t>=off) ? sums[t-off] : 0;
    __syncthreads();
    sums[t] += v;
    __syncthreads();
  }
  int excl = (t==0) ? 0 : sums[t-1];
  #pragma unroll
  for (int i=0;i<32;i++) rowp[base+i] = excl + loc[i];
  if (t==1023) rowp[NN] = sums[1023];
}

__global__ __launch_bounds__(256) void fill_kernel(const int* __restrict__ src, const int* __restrict__ dst,
                                                   const int* __restrict__ rowp, int* __restrict__ cursor,
                                                   int* __restrict__ csr){
  int e = blockIdx.x*256 + threadIdx.x;
  if (e < EDGES){
    int d = dst[e];
    int pos = atomicAdd(&cursor[d], 1);
    csr[rowp[d] + pos] = src[e];
  }
}

// ---------- small-tensor conversion to canonical f32 ----------
__global__ __launch_bounds__(512) void bcvt_kernel(const int* __restrict__ flags,
    const void* b1, const void* b2, const void* sW1, const void* sW2,
    const void* sb1, const void* sb2,
    float* b1c, float* b2c, float* sW1c, float* sW2c, float* sbc)
{
  int t = threadIdx.x;
  int f = flags[0];
  #define CV(p,i) (f ? ((const float*)(p))[i] : b2f(((const u16*)(p))[i]))
  b1c[t]  = CV(b1, t);
  b2c[t]  = CV(b2, t);
  sW1c[t] = CV(sW1, t);
  sW2c[t] = CV(sW2, t);
  if (t==0){ sbc[0] = CV(sb1,0); sbc[1] = CV(sb2,0); }
  #undef CV
}

// ---------- weight transpose + hi/lo bf16 split: WT*[n][k] = split(W[k][n]) ----------
__global__ void tsplit_kernel(const int* __restrict__ flags, const void* __restrict__ W,
                              u16* __restrict__ WTh, u16* __restrict__ WTl){
  __shared__ float tile[32][33];
  int f = flags[0];
  int bx = blockIdx.x*32, by = blockIdx.y*32;
  int tx = threadIdx.x, ty = threadIdx.y; // (32,8)
  #pragma unroll
  for (int i=0;i<4;i++){
    size_t idx = (size_t)(by+ty+i*8)*D + bx+tx;
    tile[ty+i*8][tx] = f ? ((const float*)W)[idx] : b2f(((const u16*)W)[idx]);
  }
  __syncthreads();
  #pragma unroll
  for (int i=0;i<4;i++){
    float v = tile[tx][ty+i*8];
    u16 h = f2b(v);
    size_t o = (size_t)(bx+ty+i*8)*D + by+tx;
    WTh[o] = h;
    WTl[o] = f2b(v - b2f(h));
  }
}

// ---------------- GEMM: C[row][col] = (A @ W) * rowscale[row] ----------------
// A: f32 (or bf16 per aflag). B pre-split bf16 hi/lo, BT row-major [N][K].
// 128x128 tile, BK=32, 4 waves (2x2), 16x16x32 MFMA, 2x2 split w/ 3 products.

__global__ __launch_bounds__(256) void gemm_splitAB(
    const void* __restrict__ A, const int* __restrict__ aflag,
    const u16* __restrict__ BTh, const u16* __restrict__ BTl,
    float* __restrict__ C, const float* __restrict__ rowscale)
{
  __shared__ alignas(16) u16 Ah[4][128][8], Alo[4][128][8];
  __shared__ alignas(16) u16 Bh[4][128][8], Bl[4][128][8];
  int t = threadIdx.x;
  int brow = blockIdx.x*128, bcol = blockIdx.y*128;
  int wid = t>>6, lane = t&63;
  int wm = wid>>1, wn = wid&1;
  f32x4 acc[4][4] = {};
  int sr = t>>1, scb = (t&1)*16;
  int q0 = scb>>3;
  int q = lane>>4, r = lane&15;
  const int af = aflag[0];
  const float* gAf = (const float*)A + (size_t)(brow+sr)*D + scb;
  const u16*   gAb = (const u16*)A   + (size_t)(brow+sr)*D + scb;
  const u16* gBh = BTh + (size_t)(bcol+sr)*D + scb;
  const u16* gBl = BTl + (size_t)(bcol+sr)*D + scb;

  for (int kt=0; kt<D; kt+=32){
    __syncthreads();
    float av[16];
    if (af){
      *(float4*)(av)    = *(const float4*)(gAf+kt);
      *(float4*)(av+4)  = *(const float4*)(gAf+kt+4);
      *(float4*)(av+8)  = *(const float4*)(gAf+kt+8);
      *(float4*)(av+12) = *(const float4*)(gAf+kt+12);
    } else {
      int4 a0 = *(const int4*)(gAb+kt);
      int4 a1 = *(const int4*)(gAb+kt+8);
      const u16* ap = (const u16*)&a0;
      #pragma unroll
      for (int i=0;i<8;i++) av[i] = b2f(ap[i]);
      ap = (const u16*)&a1;
      #pragma unroll
      for (int i=0;i<8;i++) av[8+i] = b2f(ap[i]);
    }
    int4 b0 = *(const int4*)(gBh+kt);
    int4 b1v = *(const int4*)(gBh+kt+8);
    int4 c0 = *(const int4*)(gBl+kt);
    int4 c1 = *(const int4*)(gBl+kt+8);
    u16 hh[16], ll[16];
    #pragma unroll
    for (int i=0;i<16;i++){
      float xv = av[i];
      u16 h = f2b(xv);
      hh[i] = h;
      ll[i] = f2b(xv - b2f(h));   // exact residual
    }
    *(int4*)(&Ah[q0][sr][0])    = *(int4*)(hh);
    *(int4*)(&Ah[q0+1][sr][0])  = *(int4*)(hh+8);
    *(int4*)(&Alo[q0][sr][0])   = *(int4*)(ll);
    *(int4*)(&Alo[q0+1][sr][0]) = *(int4*)(ll+8);
    *(int4*)(&Bh[q0][sr][0])    = b0;
    *(int4*)(&Bh[q0+1][sr][0])  = b1v;
    *(int4*)(&Bl[q0][sr][0])    = c0;
    *(int4*)(&Bl[q0+1][sr][0])  = c1;
    __syncthreads();
    bf16x8 fah[4], fal[4], fbh[4], fbl[4];
    #pragma unroll
    for (int m=0;m<4;m++){
      fah[m] = *(const bf16x8*)(&Ah[q][wm*64+m*16+r][0]);
      fal[m] = *(const bf16x8*)(&Alo[q][wm*64+m*16+r][0]);
    }
    #pragma unroll
    for (int n=0;n<4;n++){
      fbh[n] = *(const bf16x8*)(&Bh[q][wn*64+n*16+r][0]);
      fbl[n] = *(const bf16x8*)(&Bl[q][wn*64+n*16+r][0]);
    }
    #pragma unroll
    for (int m=0;m<4;m++)
      #pragma unroll
      for (int n=0;n<4;n++){
        acc[m][n] = __builtin_amdgcn_mfma_f32_16x16x32_bf16(fah[m], fbh[n], acc[m][n], 0,0,0);
        acc[m][n] = __builtin_amdgcn_mfma_f32_16x16x32_bf16(fah[m], fbl[n], acc[m][n], 0,0,0);
        acc[m][n] = __builtin_amdgcn_mfma_f32_16x16x32_bf16(fal[m], fbh[n], acc[m][n], 0,0,0);
      }
  }
  #pragma unroll
  for (int m=0;m<4;m++){
    int rowb = brow + wm*64 + m*16 + q*4;
    #pragma unroll
    for (int n=0;n<4;n++){
      int col = bcol + wn*64 + n*16 + r;
      #pragma unroll
      for (int g=0; g<4; g++){
        int row = rowb + g;
        C[(size_t)row*D + col] = acc[m][n][g] * rowscale[row];
      }
    }
  }
}

// -------- edge aggregation: H[v] = relu( (sum_{u in N(v)} Y[u]) * norm_in[v] + b ) --------

__global__ __launch_bounds__(256) void agg_kernel(
    const float* __restrict__ Y, const int* __restrict__ rowp,
    const int* __restrict__ csr, const float* __restrict__ ni,
    const float* __restrict__ bias, float* __restrict__ H)
{
  int v = blockIdx.x;
  int t = threadIdx.x;
  int rp0 = rowp[v], rp1 = rowp[v+1];
  double a0 = 0.0, a1 = 0.0;
  for (int e=rp0; e<rp1; e++){
    int u = csr[e];
    const float* yr = Y + (size_t)u*D;
    a0 += (double)yr[t];
    a1 += (double)yr[t+256];
  }
  double w = (double)ni[v];
  double r0 = a0*w + (double)bias[t];
  double r1 = a1*w + (double)bias[t+256];
  H[(size_t)v*D + t]       = (float)(r0 > 0.0 ? r0 : 0.0);
  H[(size_t)v*D + t + 256] = (float)(r1 > 0.0 ? r1 : 0.0);
}

// -------- score dots: t_j[v] = h2[v] . sW_j  (one wave per node, f64 accum) --------

__global__ __launch_bounds__(256) void dot_kernel(
    const float* __restrict__ H, const float* __restrict__ sW1,
    const float* __restrict__ sW2, float* __restrict__ t1, float* __restrict__ t2)
{
  int wid = threadIdx.x>>6, lane = threadIdx.x&63;
  int v = blockIdx.x*4 + wid;
  const float4* hp = (const float4*)(H + (size_t)v*D);
  double s1 = 0.0, s2 = 0.0;
  #pragma unroll
  for (int i=0;i<2;i++){
    float4 x = hp[lane*2+i];
    float4 w1 = ((const float4*)sW1)[lane*2+i];
    float4 w2 = ((const float4*)sW2)[lane*2+i];
    const float* xv = (const float*)&x;
    const float* w1v = (const float*)&w1;
    const float* w2v = (const float*)&w2;
    #pragma unroll
    for (int j=0;j<4;j++){
      s1 += (double)xv[j] * (double)w1v[j];
      s2 += (double)xv[j] * (double)w2v[j];
    }
  }
  #pragma unroll
  for (int off=32; off>=1; off>>=1){
    s1 += __shfl_xor(s1, off);
    s2 += __shfl_xor(s2, off);
  }
  if (lane==0){ t1[v] = (float)s1; t2[v] = (float)s2; }
}

__global__ __launch_bounds__(256) void sagg_kernel(
    const float* __restrict__ t1, const float* __restrict__ t2,
    const int* __restrict__ rowp, const int* __restrict__ csr,
    const float* __restrict__ no, const float* __restrict__ ni,
    const float* __restrict__ sbc, float* __restrict__ score)
{
  int v = blockIdx.x*256 + threadIdx.x;
  if (v >= NN) return;
  double a1 = 0.0, a2 = 0.0;
  int rp1 = rowp[v+1];
  for (int e=rowp[v]; e<rp1; e++){
    int u = csr[e];
    double w = (double)no[u];
    a1 += (double)t1[u]*w;
    a2 += (double)t2[u]*w;
  }
  double wi = (double)ni[v];
  double s1 = a1*wi + (double)sbc[0];
  double s2 = a2*wi + (double)sbc[1];
  score[v] = (float)(0.5*(s1+s2));
}

// -------- per-graph stable top-K via bitonic sort of 512 (score desc, idx asc) --------

__global__ __launch_bounds__(256) void topk_kernel(const float* __restrict__ score,
    int* __restrict__ perm, float* __restrict__ gate)
{
  __shared__ unsigned long long key[NPG];
  int g = blockIdx.x, t = threadIdx.x;
  for (int i=t; i<NPG; i+=256){
    float s = score[g*NPG + i];
    unsigned u = __float_as_uint(s);
    u = (u & 0x80000000u) ? ~u : (u | 0x80000000u);  // order-preserving (ascending)
    unsigned kd = ~u;                                 // descending score
    key[i] = ((unsigned long long)kd<<32) | (unsigned)i;
  }
  __syncthreads();
  for (int k=2; k<=NPG; k<<=1){
    for (int j=k>>1; j>0; j>>=1){
      for (int i=t; i<NPG; i+=256){
        int ixj = i ^ j;
        if (ixj > i){
          unsigned long long a = key[i], b = key[ixj];
          bool up = ((i & k) == 0);
          if ((a > b) == up){ key[i] = b; key[ixj] = a; }
        }
      }
      __syncthreads();
    }
  }
  if (t < KEEP){
    unsigned long long e = key[t];
    int idx = (int)(e & 0xFFFFFFFFull);
    int node = g*NPG + idx;
    perm[g*KEEP + t] = node;
    gate[g*KEEP + t] = tanhf(score[node]);
  }
}

// -------- gated gather + readout (f32 outputs) --------

__global__ __launch_bounds__(128) void pooled_kernel(const float* __restrict__ H,
    const int* __restrict__ perm, const float* __restrict__ gate, float* __restrict__ out)
{
  int row = blockIdx.x, t = threadIdx.x;
  int node = perm[row];
  float gt = gate[row];
  float4 v = ((const float4*)(H + (size_t)node*D))[t];
  v.x *= gt; v.y *= gt; v.z *= gt; v.w *= gt;
  ((float4*)(out + (size_t)row*D))[t] = v;
}

__global__ __launch_bounds__(256) void gout_kernel(const float* __restrict__ H,
    const int* __restrict__ perm, const float* __restrict__ gate, float* __restrict__ out)
{
  __shared__ int sp[KEEP];
  __shared__ float sg[KEEP];
  int g = blockIdx.x, t = threadIdx.x;
  sp[t] = perm[g*KEEP + t];
  sg[t] = gate[g*KEEP + t];
  __syncthreads();
  int d0 = t, d1 = t + 256;
  float mx0 = -INFINITY, mx1 = -INFINITY;
  float s0 = 0.f, s1 = 0.f;
  for (int rI=0; rI<KEEP; rI++){
    const float* hr = H + (size_t)sp[rI]*D;
    float gt = sg[rI];
    float v0 = hr[d0]*gt, v1 = hr[d1]*gt;
    mx0 = fmaxf(mx0, v0); mx1 = fmaxf(mx1, v1);
    s0 += v0; s1 += v1;
  }
  float* go = out + (size_t)g*1024;
  go[d0] = mx0; go[d1] = mx1;
  go[512+d0] = s0; go[512+d1] = s1;
}

// ---------------- launch ----------------

extern "C" void kernel_launch(void* const* d_in, const int* in_sizes, int n_in,
                              void* d_out, int out_size, void* d_ws, size_t ws_size,
                              hipStream_t stream)
{
  (void)in_sizes; (void)n_in; (void)out_size; (void)ws_size;
  const void* x   = d_in[0];
  const int* src  = (const int*)d_in[1];
  const int* dst  = (const int*)d_in[2];
  const void* W1  = d_in[3];
  const void* b1  = d_in[4];
  const void* W2  = d_in[5];
  const void* b2  = d_in[6];
  const void* sW1 = d_in[7];
  const void* sb1 = d_in[8];
  const void* sW2 = d_in[9];
  const void* sb2 = d_in[10];
  float* out = (float*)d_out;

  char* ws = (char*)d_ws;
  size_t off = 0;
  auto alloc = [&](size_t bytes){ void* p = ws + off; off += (bytes + 255) & ~(size_t)255; return p; };
  int*   flags  = (int*)  alloc(2*4);
  int*   dego   = (int*)  alloc((size_t)NN*4);     // dego, degi, cursor contiguous
  int*   degi   = (int*)  alloc((size_t)NN*4);
  int*   cursor = (int*)  alloc((size_t)NN*4);
  float* no     = (float*)alloc((size_t)NN*4);
  float* ni     = (float*)alloc((size_t)NN*4);
  int*   rowp   = (int*)  alloc((size_t)(NN+1)*4);
  float* t1     = (float*)alloc((size_t)NN*4);
  float* t2     = (float*)alloc((size_t)NN*4);
  float* score  = (float*)alloc((size_t)NN*4);
  int*   perm   = (int*)  alloc((size_t)NB*KEEP*4);
  float* gate   = (float*)alloc((size_t)NB*KEEP*4);
  float* b1c    = (float*)alloc((size_t)D*4);
  float* b2c    = (float*)alloc((size_t)D*4);
  float* sW1c   = (float*)alloc((size_t)D*4);
  float* sW2c   = (float*)alloc((size_t)D*4);
  float* sbc    = (float*)alloc(2*4);
  u16*   W1Th   = (u16*)  alloc((size_t)D*D*2);
  u16*   W1Tl   = (u16*)  alloc((size_t)D*D*2);
  u16*   W2Th   = (u16*)  alloc((size_t)D*D*2);
  u16*   W2Tl   = (u16*)  alloc((size_t)D*D*2);
  int*   csr    = (int*)  alloc((size_t)EDGES*4);
  float* Y      = (float*)alloc((size_t)NN*D*4);
  float* H      = (float*)alloc((size_t)NN*D*4);

  zero3_kernel<<<(3*NN)/256, 256, 0, stream>>>(dego);
  detect_kernel<<<1, 256, 0, stream>>>((const u16*)x, flags);
  deg_kernel <<<EDGES/256, 256, 0, stream>>>(src, dst, dego, degi);
  norm_kernel<<<NN/256,    256, 0, stream>>>(dego, degi, no, ni);
  scan_kernel<<<1,        1024, 0, stream>>>(degi, rowp);
  fill_kernel<<<EDGES/256, 256, 0, stream>>>(src, dst, rowp, cursor, csr);
  bcvt_kernel<<<1, 512, 0, stream>>>(flags, b1, b2, sW1, sW2, sb1, sb2, b1c, b2c, sW1c, sW2c, sbc);
  tsplit_kernel<<<dim3(16,16), dim3(32,8), 0, stream>>>(flags, W1, W1Th, W1Tl);
  tsplit_kernel<<<dim3(16,16), dim3(32,8), 0, stream>>>(flags, W2, W2Th, W2Tl);

  gemm_splitAB<<<dim3(NN/128, 4), 256, 0, stream>>>(x, flags,   W1Th, W1Tl, Y, no);
  agg_kernel  <<<NN, 256, 0, stream>>>(Y, rowp, csr, ni, b1c, H);        // H = h1
  gemm_splitAB<<<dim3(NN/128, 4), 256, 0, stream>>>(H, flags+1, W2Th, W2Tl, Y, no);
  agg_kernel  <<<NN, 256, 0, stream>>>(Y, rowp, csr, ni, b2c, H);        // H = h2

  dot_kernel <<<NN/4,   256, 0, stream>>>(H, sW1c, sW2c, t1, t2);
  sagg_kernel<<<NN/256, 256, 0, stream>>>(t1, t2, rowp, csr, no, ni, sbc, score);
  topk_kernel<<<NB,     256, 0, stream>>>(score, perm, gate);

  pooled_kernel<<<NB*KEEP, 128, 0, stream>>>(H, perm, gate, out);
  gout_kernel  <<<NB,      256, 0, stream>>>(H, perm, gate, out + (size_t)NB*KEEP*D);
}

// Round 4
// 426.164 us; speedup vs baseline: 1.1892x; 1.1892x over previous
//
#include <hip/hip_runtime.h>
#include <math.h>

typedef unsigned short u16;
typedef __attribute__((ext_vector_type(8))) short bf16x8;
typedef __attribute__((ext_vector_type(4))) float f32x4;

#define NN 32768      // total nodes
#define EDGES 524288  // total edges
#define NB 64         // graphs
#define NPG 512       // nodes per graph
#define KEEP 256      // kept per graph
#define D 512         // feature dim

__device__ __forceinline__ float b2f(u16 h){ return __uint_as_float(((unsigned)h)<<16); }
__device__ __forceinline__ u16 f2b(float f){
  unsigned u = __float_as_uint(f);
  unsigned r = u + 0x7FFFu + ((u>>16)&1u);   // RNE
  return (u16)(r>>16);
}

// ---------- dtype detection: are float inputs f32 (flag=1) or bf16 (flag=0)? ----------
__global__ __launch_bounds__(256) void detect_kernel(const u16* __restrict__ xb, int* __restrict__ flags){
  __shared__ int cnt;
  if (threadIdx.x==0) cnt = 0;
  __syncthreads();
  u16 v = xb[threadIdx.x];
  int e = (v>>7)&0xFF;
  if (e > 140) atomicAdd(&cnt, 1);
  __syncthreads();
  if (threadIdx.x==0){ flags[0] = (cnt > 8) ? 1 : 0; flags[1] = 1; }
}

__global__ __launch_bounds__(256) void zero3_kernel(int* __restrict__ p){
  p[blockIdx.x*256 + threadIdx.x] = 0;   // covers dego, degi, cursor (3*NN ints)
}

// ---------------- graph preprocessing ----------------

__global__ __launch_bounds__(256) void deg_kernel(const int* __restrict__ src, const int* __restrict__ dst,
                                                  int* __restrict__ dego, int* __restrict__ degi){
  int e = blockIdx.x*256 + threadIdx.x;
  if (e < EDGES){
    atomicAdd(&dego[src[e]], 1);
    atomicAdd(&degi[dst[e]], 1);
  }
}

__global__ __launch_bounds__(256) void norm_kernel(const int* __restrict__ dego, const int* __restrict__ degi,
                                                   float* __restrict__ no, float* __restrict__ ni){
  int v = blockIdx.x*256 + threadIdx.x;
  if (v < NN){
    int a = dego[v]; if (a < 1) a = 1;
    int b = degi[v]; if (b < 1) b = 1;
    no[v] = (float)(1.0/sqrt((double)a));
    ni[v] = (float)(1.0/sqrt((double)b));
  }
}

__global__ __launch_bounds__(1024) void scan_kernel(const int* __restrict__ degi, int* __restrict__ rowp){
  __shared__ int sums[1024];
  int t = threadIdx.x;
  int base = t*32;
  int loc[32];
  int s = 0;
  #pragma unroll
  for (int i=0;i<32;i++){ loc[i] = s; s += degi[base+i]; }
  sums[t] = s;
  __syncthreads();
  for (int off=1; off<1024; off<<=1){
    int v = (t>=off) ? sums[t-off] : 0;
    __syncthreads();
    sums[t] += v;
    __syncthreads();
  }
  int excl = (t==0) ? 0 : sums[t-1];
  #pragma unroll
  for (int i=0;i<32;i++) rowp[base+i] = excl + loc[i];
  if (t==1023) rowp[NN] = sums[1023];
}

__global__ __launch_bounds__(256) void fill_kernel(const int* __restrict__ src, const int* __restrict__ dst,
                                                   const int* __restrict__ rowp, int* __restrict__ cursor,
                                                   int* __restrict__ csr){
  int e = blockIdx.x*256 + threadIdx.x;
  if (e < EDGES){
    int d = dst[e];
    int pos = atomicAdd(&cursor[d], 1);
    csr[rowp[d] + pos] = src[e];
  }
}

// ---------- small-tensor conversion to canonical f32 ----------
__global__ __launch_bounds__(512) void bcvt_kernel(const int* __restrict__ flags,
    const void* b1, const void* b2, const void* sW1, const void* sW2,
    const void* sb1, const void* sb2,
    float* b1c, float* b2c, float* sW1c, float* sW2c, float* sbc)
{
  int t = threadIdx.x;
  int f = flags[0];
  #define CV(p,i) (f ? ((const float*)(p))[i] : b2f(((const u16*)(p))[i]))
  b1c[t]  = CV(b1, t);
  b2c[t]  = CV(b2, t);
  sW1c[t] = CV(sW1, t);
  sW2c[t] = CV(sW2, t);
  if (t==0){ sbc[0] = CV(sb1,0); sbc[1] = CV(sb2,0); }
  #undef CV
}

// ---------- weight transpose + hi/lo bf16 split ----------
__global__ void tsplit_kernel(const int* __restrict__ flags, const void* __restrict__ W,
                              u16* __restrict__ WTh, u16* __restrict__ WTl){
  __shared__ float tile[32][33];
  int f = flags[0];
  int bx = blockIdx.x*32, by = blockIdx.y*32;
  int tx = threadIdx.x, ty = threadIdx.y; // (32,8)
  #pragma unroll
  for (int i=0;i<4;i++){
    size_t idx = (size_t)(by+ty+i*8)*D + bx+tx;
    tile[ty+i*8][tx] = f ? ((const float*)W)[idx] : b2f(((const u16*)W)[idx]);
  }
  __syncthreads();
  #pragma unroll
  for (int i=0;i<4;i++){
    float v = tile[tx][ty+i*8];
    u16 h = f2b(v);
    size_t o = (size_t)(bx+ty+i*8)*D + by+tx;
    WTh[o] = h;
    WTl[o] = f2b(v - b2f(h));
  }
}

// ---------------- GEMM: C[row][col] = (A @ W) * rowscale[row] ----------------

__global__ __launch_bounds__(256) void gemm_splitAB(
    const void* __restrict__ A, const int* __restrict__ aflag,
    const u16* __restrict__ BTh, const u16* __restrict__ BTl,
    float* __restrict__ C, const float* __restrict__ rowscale)
{
  __shared__ alignas(16) u16 Ah[4][128][8], Alo[4][128][8];
  __shared__ alignas(16) u16 Bh[4][128][8], Bl[4][128][8];
  int t = threadIdx.x;
  int brow = blockIdx.x*128, bcol = blockIdx.y*128;
  int wid = t>>6, lane = t&63;
  int wm = wid>>1, wn = wid&1;
  f32x4 acc[4][4] = {};
  int sr = t>>1, scb = (t&1)*16;
  int q0 = scb>>3;
  int q = lane>>4, r = lane&15;
  const int af = aflag[0];
  const float* gAf = (const float*)A + (size_t)(brow+sr)*D + scb;
  const u16*   gAb = (const u16*)A   + (size_t)(brow+sr)*D + scb;
  const u16* gBh = BTh + (size_t)(bcol+sr)*D + scb;
  const u16* gBl = BTl + (size_t)(bcol+sr)*D + scb;

  for (int kt=0; kt<D; kt+=32){
    __syncthreads();
    float av[16];
    if (af){
      *(float4*)(av)    = *(const float4*)(gAf+kt);
      *(float4*)(av+4)  = *(const float4*)(gAf+kt+4);
      *(float4*)(av+8)  = *(const float4*)(gAf+kt+8);
      *(float4*)(av+12) = *(const float4*)(gAf+kt+12);
    } else {
      int4 a0 = *(const int4*)(gAb+kt);
      int4 a1 = *(const int4*)(gAb+kt+8);
      const u16* ap = (const u16*)&a0;
      #pragma unroll
      for (int i=0;i<8;i++) av[i] = b2f(ap[i]);
      ap = (const u16*)&a1;
      #pragma unroll
      for (int i=0;i<8;i++) av[8+i] = b2f(ap[i]);
    }
    int4 b0 = *(const int4*)(gBh+kt);
    int4 b1v = *(const int4*)(gBh+kt+8);
    int4 c0 = *(const int4*)(gBl+kt);
    int4 c1 = *(const int4*)(gBl+kt+8);
    u16 hh[16], ll[16];
    #pragma unroll
    for (int i=0;i<16;i++){
      float xv = av[i];
      u16 h = f2b(xv);
      hh[i] = h;
      ll[i] = f2b(xv - b2f(h));
    }
    *(int4*)(&Ah[q0][sr][0])    = *(int4*)(hh);
    *(int4*)(&Ah[q0+1][sr][0])  = *(int4*)(hh+8);
    *(int4*)(&Alo[q0][sr][0])   = *(int4*)(ll);
    *(int4*)(&Alo[q0+1][sr][0]) = *(int4*)(ll+8);
    *(int4*)(&Bh[q0][sr][0])    = b0;
    *(int4*)(&Bh[q0+1][sr][0])  = b1v;
    *(int4*)(&Bl[q0][sr][0])    = c0;
    *(int4*)(&Bl[q0+1][sr][0])  = c1;
    __syncthreads();
    bf16x8 fah[4], fal[4], fbh[4], fbl[4];
    #pragma unroll
    for (int m=0;m<4;m++){
      fah[m] = *(const bf16x8*)(&Ah[q][wm*64+m*16+r][0]);
      fal[m] = *(const bf16x8*)(&Alo[q][wm*64+m*16+r][0]);
    }
    #pragma unroll
    for (int n=0;n<4;n++){
      fbh[n] = *(const bf16x8*)(&Bh[q][wn*64+n*16+r][0]);
      fbl[n] = *(const bf16x8*)(&Bl[q][wn*64+n*16+r][0]);
    }
    #pragma unroll
    for (int m=0;m<4;m++)
      #pragma unroll
      for (int n=0;n<4;n++){
        acc[m][n] = __builtin_amdgcn_mfma_f32_16x16x32_bf16(fah[m], fbh[n], acc[m][n], 0,0,0);
        acc[m][n] = __builtin_amdgcn_mfma_f32_16x16x32_bf16(fah[m], fbl[n], acc[m][n], 0,0,0);
        acc[m][n] = __builtin_amdgcn_mfma_f32_16x16x32_bf16(fal[m], fbh[n], acc[m][n], 0,0,0);
      }
  }
  #pragma unroll
  for (int m=0;m<4;m++){
    int rowb = brow + wm*64 + m*16 + q*4;
    #pragma unroll
    for (int n=0;n<4;n++){
      int col = bcol + wn*64 + n*16 + r;
      #pragma unroll
      for (int g=0; g<4; g++){
        int row = rowb + g;
        C[(size_t)row*D + col] = acc[m][n][g] * rowscale[row];
      }
    }
  }
}

// -------- edge aggregation: H[v] = relu( (sum_{u in N(v)} Y[u]) * norm_in[v] + b ) --------
// Graph->XCD pinned block mapping: dispatch i -> node of graph g with g%8 == i%8,
// so each graph's 1MB Y-panel stays in one XCD's L2.
// Optional fused score dots (for the h2 pass): t1[v]=h.sW1, t2[v]=h.sW2 (f64).

__global__ __launch_bounds__(256) void agg_kernel(
    const float* __restrict__ Y, const int* __restrict__ rowp,
    const int* __restrict__ csr, const float* __restrict__ ni,
    const float* __restrict__ bias, float* __restrict__ H,
    const float* __restrict__ sW1, const float* __restrict__ sW2,
    float* __restrict__ t1, float* __restrict__ t2, int do_scores)
{
  int i = blockIdx.x;
  int xcd = i & 7, j = i >> 3;
  int v = (xcd + 8*(j >> 9))*NPG + (j & 511);
  int t = threadIdx.x;
  int rp0 = rowp[v], rp1 = rowp[v+1];
  double a0 = 0.0, a1 = 0.0;
  for (int e=rp0; e<rp1; e++){
    int u = csr[e];
    const float* yr = Y + (size_t)u*D;
    a0 += (double)yr[t];
    a1 += (double)yr[t+256];
  }
  double w = (double)ni[v];
  double r0 = a0*w + (double)bias[t];
  double r1 = a1*w + (double)bias[t+256];
  if (r0 < 0.0) r0 = 0.0;
  if (r1 < 0.0) r1 = 0.0;
  H[(size_t)v*D + t]       = (float)r0;
  H[(size_t)v*D + t + 256] = (float)r1;

  if (do_scores){
    double p1 = r0*(double)sW1[t] + r1*(double)sW1[t+256];
    double p2 = r0*(double)sW2[t] + r1*(double)sW2[t+256];
    #pragma unroll
    for (int off=32; off>=1; off>>=1){
      p1 += __shfl_xor(p1, off);
      p2 += __shfl_xor(p2, off);
    }
    __shared__ double red1[4], red2[4];
    int wid = t>>6, lane = t&63;
    if (lane==0){ red1[wid] = p1; red2[wid] = p2; }
    __syncthreads();
    if (t==0){
      t1[v] = (float)(red1[0]+red1[1]+red1[2]+red1[3]);
      t2[v] = (float)(red2[0]+red2[1]+red2[2]+red2[3]);
    }
  }
}

// -------- score aggregation --------

__global__ __launch_bounds__(256) void sagg_kernel(
    const float* __restrict__ t1, const float* __restrict__ t2,
    const int* __restrict__ rowp, const int* __restrict__ csr,
    const float* __restrict__ no, const float* __restrict__ ni,
    const float* __restrict__ sbc, float* __restrict__ score)
{
  int v = blockIdx.x*256 + threadIdx.x;
  if (v >= NN) return;
  double a1 = 0.0, a2 = 0.0;
  int rp1 = rowp[v+1];
  for (int e=rowp[v]; e<rp1; e++){
    int u = csr[e];
    double w = (double)no[u];
    a1 += (double)t1[u]*w;
    a2 += (double)t2[u]*w;
  }
  double wi = (double)ni[v];
  double s1 = a1*wi + (double)sbc[0];
  double s2 = a2*wi + (double)sbc[1];
  score[v] = (float)(0.5*(s1+s2));
}

// -------- per-graph stable top-K via bitonic sort of 512 (score desc, idx asc) --------

__global__ __launch_bounds__(256) void topk_kernel(const float* __restrict__ score,
    int* __restrict__ perm, float* __restrict__ gate)
{
  __shared__ unsigned long long key[NPG];
  int g = blockIdx.x, t = threadIdx.x;
  for (int i=t; i<NPG; i+=256){
    float s = score[g*NPG + i];
    unsigned u = __float_as_uint(s);
    u = (u & 0x80000000u) ? ~u : (u | 0x80000000u);
    unsigned kd = ~u;
    key[i] = ((unsigned long long)kd<<32) | (unsigned)i;
  }
  __syncthreads();
  for (int k=2; k<=NPG; k<<=1){
    for (int j=k>>1; j>0; j>>=1){
      for (int i=t; i<NPG; i+=256){
        int ixj = i ^ j;
        if (ixj > i){
          unsigned long long a = key[i], b = key[ixj];
          bool up = ((i & k) == 0);
          if ((a > b) == up){ key[i] = b; key[ixj] = a; }
        }
      }
      __syncthreads();
    }
  }
  if (t < KEEP){
    unsigned long long e = key[t];
    int idx = (int)(e & 0xFFFFFFFFull);
    int node = g*NPG + idx;
    perm[g*KEEP + t] = node;
    gate[g*KEEP + t] = tanhf(score[node]);
  }
}

// -------- gated gather + readout (f32 outputs) --------

__global__ __launch_bounds__(128) void pooled_kernel(const float* __restrict__ H,
    const int* __restrict__ perm, const float* __restrict__ gate, float* __restrict__ out)
{
  int i = blockIdx.x;
  int xcd = i & 7, j = i >> 3;
  int row = (xcd + 8*(j >> 8))*KEEP + (j & 255);
  int t = threadIdx.x;
  int node = perm[row];
  float gt = gate[row];
  float4 v = ((const float4*)(H + (size_t)node*D))[t];
  v.x *= gt; v.y *= gt; v.z *= gt; v.w *= gt;
  ((float4*)(out + (size_t)row*D))[t] = v;
}

__global__ __launch_bounds__(256) void gout_kernel(const float* __restrict__ H,
    const int* __restrict__ perm, const float* __restrict__ gate, float* __restrict__ out)
{
  __shared__ int sp[KEEP];
  __shared__ float sg[KEEP];
  int g = blockIdx.x, t = threadIdx.x;
  sp[t] = perm[g*KEEP + t];
  sg[t] = gate[g*KEEP + t];
  __syncthreads();
  int d0 = t, d1 = t + 256;
  float mx0 = -INFINITY, mx1 = -INFINITY;
  float s0 = 0.f, s1 = 0.f;
  for (int rI=0; rI<KEEP; rI++){
    const float* hr = H + (size_t)sp[rI]*D;
    float gt = sg[rI];
    float v0 = hr[d0]*gt, v1 = hr[d1]*gt;
    mx0 = fmaxf(mx0, v0); mx1 = fmaxf(mx1, v1);
    s0 += v0; s1 += v1;
  }
  float* go = out + (size_t)g*1024;
  go[d0] = mx0; go[d1] = mx1;
  go[512+d0] = s0; go[512+d1] = s1;
}

// ---------------- launch ----------------

extern "C" void kernel_launch(void* const* d_in, const int* in_sizes, int n_in,
                              void* d_out, int out_size, void* d_ws, size_t ws_size,
                              hipStream_t stream)
{
  (void)in_sizes; (void)n_in; (void)out_size; (void)ws_size;
  const void* x   = d_in[0];
  const int* src  = (const int*)d_in[1];
  const int* dst  = (const int*)d_in[2];
  const void* W1  = d_in[3];
  const void* b1  = d_in[4];
  const void* W2  = d_in[5];
  const void* b2  = d_in[6];
  const void* sW1 = d_in[7];
  const void* sb1 = d_in[8];
  const void* sW2 = d_in[9];
  const void* sb2 = d_in[10];
  float* out = (float*)d_out;

  char* ws = (char*)d_ws;
  size_t off = 0;
  auto alloc = [&](size_t bytes){ void* p = ws + off; off += (bytes + 255) & ~(size_t)255; return p; };
  int*   flags  = (int*)  alloc(2*4);
  int*   dego   = (int*)  alloc((size_t)NN*4);     // dego, degi, cursor contiguous
  int*   degi   = (int*)  alloc((size_t)NN*4);
  int*   cursor = (int*)  alloc((size_t)NN*4);
  float* no     = (float*)alloc((size_t)NN*4);
  float* ni     = (float*)alloc((size_t)NN*4);
  int*   rowp   = (int*)  alloc((size_t)(NN+1)*4);
  float* t1     = (float*)alloc((size_t)NN*4);
  float* t2     = (float*)alloc((size_t)NN*4);
  float* score  = (float*)alloc((size_t)NN*4);
  int*   perm   = (int*)  alloc((size_t)NB*KEEP*4);
  float* gate   = (float*)alloc((size_t)NB*KEEP*4);
  float* b1c    = (float*)alloc((size_t)D*4);
  float* b2c    = (float*)alloc((size_t)D*4);
  float* sW1c   = (float*)alloc((size_t)D*4);
  float* sW2c   = (float*)alloc((size_t)D*4);
  float* sbc    = (float*)alloc(2*4);
  u16*   W1Th   = (u16*)  alloc((size_t)D*D*2);
  u16*   W1Tl   = (u16*)  alloc((size_t)D*D*2);
  u16*   W2Th   = (u16*)  alloc((size_t)D*D*2);
  u16*   W2Tl   = (u16*)  alloc((size_t)D*D*2);
  int*   csr    = (int*)  alloc((size_t)EDGES*4);
  float* Y      = (float*)alloc((size_t)NN*D*4);
  float* H      = (float*)alloc((size_t)NN*D*4);

  zero3_kernel<<<(3*NN)/256, 256, 0, stream>>>(dego);
  detect_kernel<<<1, 256, 0, stream>>>((const u16*)x, flags);
  deg_kernel <<<EDGES/256, 256, 0, stream>>>(src, dst, dego, degi);
  norm_kernel<<<NN/256,    256, 0, stream>>>(dego, degi, no, ni);
  scan_kernel<<<1,        1024, 0, stream>>>(degi, rowp);
  fill_kernel<<<EDGES/256, 256, 0, stream>>>(src, dst, rowp, cursor, csr);
  bcvt_kernel<<<1, 512, 0, stream>>>(flags, b1, b2, sW1, sW2, sb1, sb2, b1c, b2c, sW1c, sW2c, sbc);
  tsplit_kernel<<<dim3(16,16), dim3(32,8), 0, stream>>>(flags, W1, W1Th, W1Tl);
  tsplit_kernel<<<dim3(16,16), dim3(32,8), 0, stream>>>(flags, W2, W2Th, W2Tl);

  gemm_splitAB<<<dim3(NN/128, 4), 256, 0, stream>>>(x, flags,   W1Th, W1Tl, Y, no);
  agg_kernel  <<<NN, 256, 0, stream>>>(Y, rowp, csr, ni, b1c, H,
                                       nullptr, nullptr, nullptr, nullptr, 0);   // H = h1
  gemm_splitAB<<<dim3(NN/128, 4), 256, 0, stream>>>(H, flags+1, W2Th, W2Tl, Y, no);
  agg_kernel  <<<NN, 256, 0, stream>>>(Y, rowp, csr, ni, b2c, H,
                                       sW1c, sW2c, t1, t2, 1);                   // H = h2 + score dots

  sagg_kernel<<<NN/256, 256, 0, stream>>>(t1, t2, rowp, csr, no, ni, sbc, score);
  topk_kernel<<<NB,     256, 0, stream>>>(score, perm, gate);

  pooled_kernel<<<NB*KEEP, 128, 0, stream>>>(H, perm, gate, out);
  gout_kernel  <<<NB,      256, 0, stream>>>(H, perm, gate, out + (size_t)NB*KEEP*D);
}

// Round 5
// 414.227 us; speedup vs baseline: 1.2234x; 1.0288x over previous
//
#include <hip/hip_runtime.h>
#include <math.h>

typedef unsigned short u16;
typedef __attribute__((ext_vector_type(8))) short bf16x8;
typedef __attribute__((ext_vector_type(4))) float f32x4;

#define NN 32768      // total nodes
#define EDGES 524288  // total edges
#define NB 64         // graphs
#define NPG 512       // nodes per graph
#define KEEP 256      // kept per graph
#define D 512         // feature dim

__device__ __forceinline__ float b2f(u16 h){ return __uint_as_float(((unsigned)h)<<16); }
__device__ __forceinline__ u16 f2b(float f){
  unsigned u = __float_as_uint(f);
  unsigned r = u + 0x7FFFu + ((u>>16)&1u);   // RNE
  return (u16)(r>>16);
}

// ---------- dtype detection: are float inputs f32 (flag=1) or bf16 (flag=0)? ----------
__global__ __launch_bounds__(256) void detect_kernel(const u16* __restrict__ xb, int* __restrict__ flags){
  __shared__ int cnt;
  if (threadIdx.x==0) cnt = 0;
  __syncthreads();
  u16 v = xb[threadIdx.x];
  int e = (v>>7)&0xFF;
  if (e > 140) atomicAdd(&cnt, 1);
  __syncthreads();
  if (threadIdx.x==0){ flags[0] = (cnt > 8) ? 1 : 0; flags[1] = 1; }
}

__global__ __launch_bounds__(256) void zero3_kernel(int* __restrict__ p){
  p[blockIdx.x*256 + threadIdx.x] = 0;   // covers dego, degi, cursor (3*NN ints)
}

// ---------------- graph preprocessing ----------------

__global__ __launch_bounds__(256) void deg_kernel(const int* __restrict__ src, const int* __restrict__ dst,
                                                  int* __restrict__ dego, int* __restrict__ degi){
  int e = blockIdx.x*256 + threadIdx.x;
  if (e < EDGES){
    atomicAdd(&dego[src[e]], 1);
    atomicAdd(&degi[dst[e]], 1);
  }
}

__global__ __launch_bounds__(256) void norm_kernel(const int* __restrict__ dego, const int* __restrict__ degi,
                                                   float* __restrict__ no, float* __restrict__ ni){
  int v = blockIdx.x*256 + threadIdx.x;
  if (v < NN){
    int a = dego[v]; if (a < 1) a = 1;
    int b = degi[v]; if (b < 1) b = 1;
    no[v] = (float)(1.0/sqrt((double)a));
    ni[v] = (float)(1.0/sqrt((double)b));
  }
}

__global__ __launch_bounds__(1024) void scan_kernel(const int* __restrict__ degi, int* __restrict__ rowp){
  __shared__ int sums[1024];
  int t = threadIdx.x;
  int base = t*32;
  int loc[32];
  int s = 0;
  #pragma unroll
  for (int i=0;i<32;i++){ loc[i] = s; s += degi[base+i]; }
  sums[t] = s;
  __syncthreads();
  for (int off=1; off<1024; off<<=1){
    int v = (t>=off) ? sums[t-off] : 0;
    __syncthreads();
    sums[t] += v;
    __syncthreads();
  }
  int excl = (t==0) ? 0 : sums[t-1];
  #pragma unroll
  for (int i=0;i<32;i++) rowp[base+i] = excl + loc[i];
  if (t==1023) rowp[NN] = sums[1023];
}

__global__ __launch_bounds__(256) void fill_kernel(const int* __restrict__ src, const int* __restrict__ dst,
                                                   const int* __restrict__ rowp, int* __restrict__ cursor,
                                                   int* __restrict__ csr){
  int e = blockIdx.x*256 + threadIdx.x;
  if (e < EDGES){
    int d = dst[e];
    int pos = atomicAdd(&cursor[d], 1);
    csr[rowp[d] + pos] = src[e];
  }
}

// ---------- small-tensor conversion to canonical f32 ----------
__global__ __launch_bounds__(512) void bcvt_kernel(const int* __restrict__ flags,
    const void* b1, const void* b2, const void* sW1, const void* sW2,
    const void* sb1, const void* sb2,
    float* b1c, float* b2c, float* sW1c, float* sW2c, float* sbc)
{
  int t = threadIdx.x;
  int f = flags[0];
  #define CV(p,i) (f ? ((const float*)(p))[i] : b2f(((const u16*)(p))[i]))
  b1c[t]  = CV(b1, t);
  b2c[t]  = CV(b2, t);
  sW1c[t] = CV(sW1, t);
  sW2c[t] = CV(sW2, t);
  if (t==0){ sbc[0] = CV(sb1,0); sbc[1] = CV(sb2,0); }
  #undef CV
}

// ---------- weight transpose + hi/lo bf16 split ----------
__global__ void tsplit_kernel(const int* __restrict__ flags, const void* __restrict__ W,
                              u16* __restrict__ WTh, u16* __restrict__ WTl){
  __shared__ float tile[32][33];
  int f = flags[0];
  int bx = blockIdx.x*32, by = blockIdx.y*32;
  int tx = threadIdx.x, ty = threadIdx.y; // (32,8)
  #pragma unroll
  for (int i=0;i<4;i++){
    size_t idx = (size_t)(by+ty+i*8)*D + bx+tx;
    tile[ty+i*8][tx] = f ? ((const float*)W)[idx] : b2f(((const u16*)W)[idx]);
  }
  __syncthreads();
  #pragma unroll
  for (int i=0;i<4;i++){
    float v = tile[tx][ty+i*8];
    u16 h = f2b(v);
    size_t o = (size_t)(bx+ty+i*8)*D + by+tx;
    WTh[o] = h;
    WTl[o] = f2b(v - b2f(h));
  }
}

// XCD-pinned block remap for 1024-block GEMM grids: 4 bcol-blocks of one brow -> same XCD
__device__ __forceinline__ void gemm_tile(int id, int& brow, int& bcol){
  int xcd = id & 7, k2 = id >> 3;          // k2: 0..127
  brow = (xcd + 8*(k2 & 31)) * 128;        // 0..255 tiles
  bcol = (k2 >> 5) * 128;                  // 0..3 tiles
}

// ---------------- GEMM (conv1): C = (A @ W) * rowscale, A f32/bf16, in-loop split ----------------

__global__ __launch_bounds__(256) void gemm_splitAB(
    const void* __restrict__ A, const int* __restrict__ aflag,
    const u16* __restrict__ BTh, const u16* __restrict__ BTl,
    float* __restrict__ C, const float* __restrict__ rowscale)
{
  __shared__ alignas(16) u16 Ah[4][128][8], Alo[4][128][8];
  __shared__ alignas(16) u16 Bh[4][128][8], Bl[4][128][8];
  int t = threadIdx.x;
  int brow, bcol;
  gemm_tile(blockIdx.x, brow, bcol);
  int wid = t>>6, lane = t&63;
  int wm = wid>>1, wn = wid&1;
  f32x4 acc[4][4] = {};
  int sr = t>>1, scb = (t&1)*16;
  int q0 = scb>>3;
  int q = lane>>4, r = lane&15;
  const int af = aflag[0];
  const float* gAf = (const float*)A + (size_t)(brow+sr)*D + scb;
  const u16*   gAb = (const u16*)A   + (size_t)(brow+sr)*D + scb;
  const u16* gBh = BTh + (size_t)(bcol+sr)*D + scb;
  const u16* gBl = BTl + (size_t)(bcol+sr)*D + scb;

  for (int kt=0; kt<D; kt+=32){
    __syncthreads();
    float av[16];
    if (af){
      *(float4*)(av)    = *(const float4*)(gAf+kt);
      *(float4*)(av+4)  = *(const float4*)(gAf+kt+4);
      *(float4*)(av+8)  = *(const float4*)(gAf+kt+8);
      *(float4*)(av+12) = *(const float4*)(gAf+kt+12);
    } else {
      int4 a0 = *(const int4*)(gAb+kt);
      int4 a1 = *(const int4*)(gAb+kt+8);
      const u16* ap = (const u16*)&a0;
      #pragma unroll
      for (int i=0;i<8;i++) av[i] = b2f(ap[i]);
      ap = (const u16*)&a1;
      #pragma unroll
      for (int i=0;i<8;i++) av[8+i] = b2f(ap[i]);
    }
    int4 b0 = *(const int4*)(gBh+kt);
    int4 b1v = *(const int4*)(gBh+kt+8);
    int4 c0 = *(const int4*)(gBl+kt);
    int4 c1 = *(const int4*)(gBl+kt+8);
    u16 hh[16], ll[16];
    #pragma unroll
    for (int i=0;i<16;i++){
      float xv = av[i];
      u16 h = f2b(xv);
      hh[i] = h;
      ll[i] = f2b(xv - b2f(h));
    }
    *(int4*)(&Ah[q0][sr][0])    = *(int4*)(hh);
    *(int4*)(&Ah[q0+1][sr][0])  = *(int4*)(hh+8);
    *(int4*)(&Alo[q0][sr][0])   = *(int4*)(ll);
    *(int4*)(&Alo[q0+1][sr][0]) = *(int4*)(ll+8);
    *(int4*)(&Bh[q0][sr][0])    = b0;
    *(int4*)(&Bh[q0+1][sr][0])  = b1v;
    *(int4*)(&Bl[q0][sr][0])    = c0;
    *(int4*)(&Bl[q0+1][sr][0])  = c1;
    __syncthreads();
    bf16x8 fah[4], fal[4], fbh[4], fbl[4];
    #pragma unroll
    for (int m=0;m<4;m++){
      fah[m] = *(const bf16x8*)(&Ah[q][wm*64+m*16+r][0]);
      fal[m] = *(const bf16x8*)(&Alo[q][wm*64+m*16+r][0]);
    }
    #pragma unroll
    for (int n=0;n<4;n++){
      fbh[n] = *(const bf16x8*)(&Bh[q][wn*64+n*16+r][0]);
      fbl[n] = *(const bf16x8*)(&Bl[q][wn*64+n*16+r][0]);
    }
    #pragma unroll
    for (int m=0;m<4;m++)
      #pragma unroll
      for (int n=0;n<4;n++){
        acc[m][n] = __builtin_amdgcn_mfma_f32_16x16x32_bf16(fah[m], fbh[n], acc[m][n], 0,0,0);
        acc[m][n] = __builtin_amdgcn_mfma_f32_16x16x32_bf16(fah[m], fbl[n], acc[m][n], 0,0,0);
        acc[m][n] = __builtin_amdgcn_mfma_f32_16x16x32_bf16(fal[m], fbh[n], acc[m][n], 0,0,0);
      }
  }
  #pragma unroll
  for (int m=0;m<4;m++){
    int rowb = brow + wm*64 + m*16 + q*4;
    #pragma unroll
    for (int n=0;n<4;n++){
      int col = bcol + wn*64 + n*16 + r;
      #pragma unroll
      for (int g=0; g<4; g++){
        int row = rowb + g;
        C[(size_t)row*D + col] = acc[m][n][g] * rowscale[row];
      }
    }
  }
}

// ---------------- GEMM (conv2): A pre-split bf16 hi/lo -> pure staging + MFMA ----------------

__global__ __launch_bounds__(256) void gemm_pre(
    const u16* __restrict__ Ahg, const u16* __restrict__ Alg,
    const u16* __restrict__ BTh, const u16* __restrict__ BTl,
    float* __restrict__ C, const float* __restrict__ rowscale)
{
  __shared__ alignas(16) u16 Ah[4][128][8], Alo[4][128][8];
  __shared__ alignas(16) u16 Bh[4][128][8], Bl[4][128][8];
  int t = threadIdx.x;
  int brow, bcol;
  gemm_tile(blockIdx.x, brow, bcol);
  int wid = t>>6, lane = t&63;
  int wm = wid>>1, wn = wid&1;
  f32x4 acc[4][4] = {};
  int sr = t>>1, scb = (t&1)*16;
  int q0 = scb>>3;
  int q = lane>>4, r = lane&15;
  const u16* gAh = Ahg + (size_t)(brow+sr)*D + scb;
  const u16* gAl = Alg + (size_t)(brow+sr)*D + scb;
  const u16* gBh = BTh + (size_t)(bcol+sr)*D + scb;
  const u16* gBl = BTl + (size_t)(bcol+sr)*D + scb;

  for (int kt=0; kt<D; kt+=32){
    int4 a0 = *(const int4*)(gAh+kt);
    int4 a1 = *(const int4*)(gAh+kt+8);
    int4 l0 = *(const int4*)(gAl+kt);
    int4 l1 = *(const int4*)(gAl+kt+8);
    int4 b0 = *(const int4*)(gBh+kt);
    int4 b1v = *(const int4*)(gBh+kt+8);
    int4 c0 = *(const int4*)(gBl+kt);
    int4 c1 = *(const int4*)(gBl+kt+8);
    __syncthreads();
    *(int4*)(&Ah[q0][sr][0])    = a0;
    *(int4*)(&Ah[q0+1][sr][0])  = a1;
    *(int4*)(&Alo[q0][sr][0])   = l0;
    *(int4*)(&Alo[q0+1][sr][0]) = l1;
    *(int4*)(&Bh[q0][sr][0])    = b0;
    *(int4*)(&Bh[q0+1][sr][0])  = b1v;
    *(int4*)(&Bl[q0][sr][0])    = c0;
    *(int4*)(&Bl[q0+1][sr][0])  = c1;
    __syncthreads();
    bf16x8 fah[4], fal[4], fbh[4], fbl[4];
    #pragma unroll
    for (int m=0;m<4;m++){
      fah[m] = *(const bf16x8*)(&Ah[q][wm*64+m*16+r][0]);
      fal[m] = *(const bf16x8*)(&Alo[q][wm*64+m*16+r][0]);
    }
    #pragma unroll
    for (int n=0;n<4;n++){
      fbh[n] = *(const bf16x8*)(&Bh[q][wn*64+n*16+r][0]);
      fbl[n] = *(const bf16x8*)(&Bl[q][wn*64+n*16+r][0]);
    }
    #pragma unroll
    for (int m=0;m<4;m++)
      #pragma unroll
      for (int n=0;n<4;n++){
        acc[m][n] = __builtin_amdgcn_mfma_f32_16x16x32_bf16(fah[m], fbh[n], acc[m][n], 0,0,0);
        acc[m][n] = __builtin_amdgcn_mfma_f32_16x16x32_bf16(fah[m], fbl[n], acc[m][n], 0,0,0);
        acc[m][n] = __builtin_amdgcn_mfma_f32_16x16x32_bf16(fal[m], fbh[n], acc[m][n], 0,0,0);
      }
  }
  #pragma unroll
  for (int m=0;m<4;m++){
    int rowb = brow + wm*64 + m*16 + q*4;
    #pragma unroll
    for (int n=0;n<4;n++){
      int col = bcol + wn*64 + n*16 + r;
      #pragma unroll
      for (int g=0; g<4; g++){
        int row = rowb + g;
        C[(size_t)row*D + col] = acc[m][n][g] * rowscale[row];
      }
    }
  }
}

// -------- edge aggregation: relu( (sum_{u in N(v)} Y[u]) * ni[v] + b ) --------
// 2 nodes/block, 128 threads/node, float4 per thread. XCD-pinned per graph.
// mode 0: write split bf16 hi/lo (feeds gemm_pre).  mode 1: write f32 H + fused score dots.

__global__ __launch_bounds__(256) void agg_kernel(
    const float* __restrict__ Y, const int* __restrict__ rowp,
    const int* __restrict__ csr, const float* __restrict__ ni,
    const float* __restrict__ bias, float* __restrict__ H,
    u16* __restrict__ Hh, u16* __restrict__ Hl,
    const float* __restrict__ sW1, const float* __restrict__ sW2,
    float* __restrict__ t1, float* __restrict__ t2, int mode)
{
  int i = blockIdx.x;
  int xcd = i & 7, j = i >> 3;              // j: 0..2047
  int half = threadIdx.x >> 7;              // node within pair
  int t = threadIdx.x & 127;                // float4 chunk
  int v = (xcd + 8*(j >> 8))*NPG + ((j & 255)*2 + half);
  int rp0 = rowp[v], rp1 = rowp[v+1];
  const float4* Yv = (const float4*)Y;
  float4 a = {0.f,0.f,0.f,0.f};
  for (int e = rp0; e < rp1; e++){
    int u = csr[e];
    float4 yv = Yv[(size_t)u*128 + t];
    a.x += yv.x; a.y += yv.y; a.z += yv.z; a.w += yv.w;
  }
  float w = ni[v];
  float4 b4 = ((const float4*)bias)[t];
  float4 rr;
  rr.x = fmaxf(a.x*w + b4.x, 0.f);
  rr.y = fmaxf(a.y*w + b4.y, 0.f);
  rr.z = fmaxf(a.z*w + b4.z, 0.f);
  rr.w = fmaxf(a.w*w + b4.w, 0.f);

  if (mode == 0){
    ushort4 hh, hl;
    hh.x = f2b(rr.x); hl.x = f2b(rr.x - b2f(hh.x));
    hh.y = f2b(rr.y); hl.y = f2b(rr.y - b2f(hh.y));
    hh.z = f2b(rr.z); hl.z = f2b(rr.z - b2f(hh.z));
    hh.w = f2b(rr.w); hl.w = f2b(rr.w - b2f(hh.w));
    *(ushort4*)(Hh + (size_t)v*D + t*4) = hh;
    *(ushort4*)(Hl + (size_t)v*D + t*4) = hl;
  } else {
    ((float4*)H)[(size_t)v*128 + t] = rr;
    float4 w1 = ((const float4*)sW1)[t];
    float4 w2 = ((const float4*)sW2)[t];
    float p1 = rr.x*w1.x + rr.y*w1.y + rr.z*w1.z + rr.w*w1.w;
    float p2 = rr.x*w2.x + rr.y*w2.y + rr.z*w2.z + rr.w*w2.w;
    #pragma unroll
    for (int off=32; off>=1; off>>=1){
      p1 += __shfl_xor(p1, off);
      p2 += __shfl_xor(p2, off);
    }
    __shared__ float red1[4], red2[4];
    int wv = threadIdx.x>>6, lane = threadIdx.x&63;
    if (lane==0){ red1[wv] = p1; red2[wv] = p2; }
    __syncthreads();
    if (t==0){
      t1[v] = red1[half*2] + red1[half*2+1];
      t2[v] = red2[half*2] + red2[half*2+1];
    }
  }
}

// -------- score aggregation --------

__global__ __launch_bounds__(256) void sagg_kernel(
    const float* __restrict__ t1, const float* __restrict__ t2,
    const int* __restrict__ rowp, const int* __restrict__ csr,
    const float* __restrict__ no, const float* __restrict__ ni,
    const float* __restrict__ sbc, float* __restrict__ score)
{
  int v = blockIdx.x*256 + threadIdx.x;
  if (v >= NN) return;
  double a1 = 0.0, a2 = 0.0;
  int rp1 = rowp[v+1];
  for (int e=rowp[v]; e<rp1; e++){
    int u = csr[e];
    double w = (double)no[u];
    a1 += (double)t1[u]*w;
    a2 += (double)t2[u]*w;
  }
  double wi = (double)ni[v];
  double s1 = a1*wi + (double)sbc[0];
  double s2 = a2*wi + (double)sbc[1];
  score[v] = (float)(0.5*(s1+s2));
}

// -------- per-graph stable top-K via bitonic sort of 512 (score desc, idx asc) --------

__global__ __launch_bounds__(256) void topk_kernel(const float* __restrict__ score,
    int* __restrict__ perm, float* __restrict__ gate)
{
  __shared__ unsigned long long key[NPG];
  int g = blockIdx.x, t = threadIdx.x;
  for (int i=t; i<NPG; i+=256){
    float s = score[g*NPG + i];
    unsigned u = __float_as_uint(s);
    u = (u & 0x80000000u) ? ~u : (u | 0x80000000u);
    unsigned kd = ~u;
    key[i] = ((unsigned long long)kd<<32) | (unsigned)i;
  }
  __syncthreads();
  for (int k=2; k<=NPG; k<<=1){
    for (int j=k>>1; j>0; j>>=1){
      for (int i=t; i<NPG; i+=256){
        int ixj = i ^ j;
        if (ixj > i){
          unsigned long long a = key[i], b = key[ixj];
          bool up = ((i & k) == 0);
          if ((a > b) == up){ key[i] = b; key[ixj] = a; }
        }
      }
      __syncthreads();
    }
  }
  if (t < KEEP){
    unsigned long long e = key[t];
    int idx = (int)(e & 0xFFFFFFFFull);
    int node = g*NPG + idx;
    perm[g*KEEP + t] = node;
    gate[g*KEEP + t] = tanhf(score[node]);
  }
}

// -------- gated gather + readout (f32 outputs) --------

__global__ __launch_bounds__(128) void pooled_kernel(const float* __restrict__ H,
    const int* __restrict__ perm, const float* __restrict__ gate, float* __restrict__ out)
{
  int i = blockIdx.x;
  int xcd = i & 7, j = i >> 3;
  int row = (xcd + 8*(j >> 8))*KEEP + (j & 255);
  int t = threadIdx.x;
  int node = perm[row];
  float gt = gate[row];
  float4 v = ((const float4*)(H + (size_t)node*D))[t];
  v.x *= gt; v.y *= gt; v.z *= gt; v.w *= gt;
  ((float4*)(out + (size_t)row*D))[t] = v;
}

__global__ __launch_bounds__(256) void gout_kernel(const float* __restrict__ H,
    const int* __restrict__ perm, const float* __restrict__ gate, float* __restrict__ out)
{
  __shared__ int sp[KEEP];
  __shared__ float sg[KEEP];
  int g = blockIdx.x, t = threadIdx.x;
  sp[t] = perm[g*KEEP + t];
  sg[t] = gate[g*KEEP + t];
  __syncthreads();
  int d0 = t, d1 = t + 256;
  float mx0 = -INFINITY, mx1 = -INFINITY;
  float s0 = 0.f, s1 = 0.f;
  for (int rI=0; rI<KEEP; rI++){
    const float* hr = H + (size_t)sp[rI]*D;
    float gt = sg[rI];
    float v0 = hr[d0]*gt, v1 = hr[d1]*gt;
    mx0 = fmaxf(mx0, v0); mx1 = fmaxf(mx1, v1);
    s0 += v0; s1 += v1;
  }
  float* go = out + (size_t)g*1024;
  go[d0] = mx0; go[d1] = mx1;
  go[512+d0] = s0; go[512+d1] = s1;
}

// ---------------- launch ----------------

extern "C" void kernel_launch(void* const* d_in, const int* in_sizes, int n_in,
                              void* d_out, int out_size, void* d_ws, size_t ws_size,
                              hipStream_t stream)
{
  (void)in_sizes; (void)n_in; (void)out_size; (void)ws_size;
  const void* x   = d_in[0];
  const int* src  = (const int*)d_in[1];
  const int* dst  = (const int*)d_in[2];
  const void* W1  = d_in[3];
  const void* b1  = d_in[4];
  const void* W2  = d_in[5];
  const void* b2  = d_in[6];
  const void* sW1 = d_in[7];
  const void* sb1 = d_in[8];
  const void* sW2 = d_in[9];
  const void* sb2 = d_in[10];
  float* out = (float*)d_out;

  char* ws = (char*)d_ws;
  size_t off = 0;
  auto alloc = [&](size_t bytes){ void* p = ws + off; off += (bytes + 255) & ~(size_t)255; return p; };
  int*   flags  = (int*)  alloc(2*4);
  int*   dego   = (int*)  alloc((size_t)NN*4);     // dego, degi, cursor contiguous
  int*   degi   = (int*)  alloc((size_t)NN*4);
  int*   cursor = (int*)  alloc((size_t)NN*4);
  float* no     = (float*)alloc((size_t)NN*4);
  float* ni     = (float*)alloc((size_t)NN*4);
  int*   rowp   = (int*)  alloc((size_t)(NN+1)*4);
  float* t1     = (float*)alloc((size_t)NN*4);
  float* t2     = (float*)alloc((size_t)NN*4);
  float* score  = (float*)alloc((size_t)NN*4);
  int*   perm   = (int*)  alloc((size_t)NB*KEEP*4);
  float* gate   = (float*)alloc((size_t)NB*KEEP*4);
  float* b1c    = (float*)alloc((size_t)D*4);
  float* b2c    = (float*)alloc((size_t)D*4);
  float* sW1c   = (float*)alloc((size_t)D*4);
  float* sW2c   = (float*)alloc((size_t)D*4);
  float* sbc    = (float*)alloc(2*4);
  u16*   W1Th   = (u16*)  alloc((size_t)D*D*2);
  u16*   W1Tl   = (u16*)  alloc((size_t)D*D*2);
  u16*   W2Th   = (u16*)  alloc((size_t)D*D*2);
  u16*   W2Tl   = (u16*)  alloc((size_t)D*D*2);
  int*   csr    = (int*)  alloc((size_t)EDGES*4);
  u16*   Hh     = (u16*)  alloc((size_t)NN*D*2);
  u16*   Hl     = (u16*)  alloc((size_t)NN*D*2);
  float* Y      = (float*)alloc((size_t)NN*D*4);
  float* H      = (float*)alloc((size_t)NN*D*4);

  zero3_kernel<<<(3*NN)/256, 256, 0, stream>>>(dego);
  detect_kernel<<<1, 256, 0, stream>>>((const u16*)x, flags);
  deg_kernel <<<EDGES/256, 256, 0, stream>>>(src, dst, dego, degi);
  norm_kernel<<<NN/256,    256, 0, stream>>>(dego, degi, no, ni);
  scan_kernel<<<1,        1024, 0, stream>>>(degi, rowp);
  fill_kernel<<<EDGES/256, 256, 0, stream>>>(src, dst, rowp, cursor, csr);
  bcvt_kernel<<<1, 512, 0, stream>>>(flags, b1, b2, sW1, sW2, sb1, sb2, b1c, b2c, sW1c, sW2c, sbc);
  tsplit_kernel<<<dim3(16,16), dim3(32,8), 0, stream>>>(flags, W1, W1Th, W1Tl);
  tsplit_kernel<<<dim3(16,16), dim3(32,8), 0, stream>>>(flags, W2, W2Th, W2Tl);

  // conv1: Y = (x @ W1) * no ; h1 = relu(agg) -> split bf16 (Hh, Hl)
  gemm_splitAB<<<1024, 256, 0, stream>>>(x, flags, W1Th, W1Tl, Y, no);
  agg_kernel  <<<NN/2, 256, 0, stream>>>(Y, rowp, csr, ni, b1c, nullptr, Hh, Hl,
                                         nullptr, nullptr, nullptr, nullptr, 0);
  // conv2: Y = (h1 @ W2) * no ; h2 = relu(agg) -> f32 H + fused score dots
  gemm_pre    <<<1024, 256, 0, stream>>>(Hh, Hl, W2Th, W2Tl, Y, no);
  agg_kernel  <<<NN/2, 256, 0, stream>>>(Y, rowp, csr, ni, b2c, H, nullptr, nullptr,
                                         sW1c, sW2c, t1, t2, 1);

  sagg_kernel<<<NN/256, 256, 0, stream>>>(t1, t2, rowp, csr, no, ni, sbc, score);
  topk_kernel<<<NB,     256, 0, stream>>>(score, perm, gate);

  pooled_kernel<<<NB*KEEP, 128, 0, stream>>>(H, perm, gate, out);
  gout_kernel  <<<NB,      256, 0, stream>>>(H, perm, gate, out + (size_t)NB*KEEP*D);
}